// Round 10
// baseline (336.109 us; speedup 1.0000x reference)
//
#include <hip/hip_runtime.h>
#include <cstdint>

// B=4, L=4096, D=3, VOCAB=8192
#define N_ROWS   16384
#define VOCAB    8192
#define THETA    0.00226f      // select threshold: ~13% of codes above
#define CAP      2048          // expect cnt~1065, sigma~30 -> +32 sigma headroom
#define MGRID    512           // main: 512 blocks x 256 thr, 8-way split, 32 rows/blk

typedef unsigned long long u64;
typedef unsigned int u32;

// d_out (floats): [0,49152) quant_ste | [49152,65536) idx | [65536] vq_loss
// d_ws: [0,32768) float4 gSel[2048] | [32768,40960) u32 gOrd[2048]
//       [40960] u32 gCnt | [41216,+2048) float part[512]

// ---------------------------------------------------------------------------
// Prep: loop-free selection, 1 code/thread, ballot-compaction, 1 global
// atomic per wave. Set order is race-dependent; correctness doesn't care
// (scan tie-break is on ORIGINAL index). Frozen ee formula.
// ---------------------------------------------------------------------------
__global__ __launch_bounds__(256) void vq_prep(
    const float* __restrict__ emb, float4* __restrict__ gSel,
    u32* __restrict__ gOrd, u32* __restrict__ gCnt)
{
    const int code = blockIdx.x * 256 + threadIdx.x;   // grid 32 -> [0,8192)
    const int lane = threadIdx.x & 63;
    const float e0 = emb[3*code+0], e1 = emb[3*code+1], e2 = emb[3*code+2];
    const float ee = __fadd_rn(__fadd_rn(__fmul_rn(e0,e0), __fmul_rn(e1,e1)),
                               __fmul_rn(e2,e2));                 // frozen
    const bool sel = ee > THETA;
    const u64 mask = __ballot(sel);
    u32 b0 = 0;
    if (lane == 0 && mask) b0 = atomicAdd(gCnt, (u32)__popcll(mask));
    b0 = __shfl(b0, 0, 64);
    if (sel) {
        const u32 pos = b0 + (u32)__popcll(mask & ((1ull << lane) - 1ull));
        if (pos < (u32)CAP) {
            gSel[pos] = make_float4(e0+e0, e1+e1, e2+e2, ee);   // doubled-e staging
            gOrd[pos] = (u32)code;
        }
    }
}

// ---------------------------------------------------------------------------
// Main: stage compacted set to LDS (vector loads), pure-VALU scan.
// gtid/8 = row, gtid&7 = candidate subset; lanes 8k..8k+7 share a row ->
// shfl_xor {1,2,4} merge. LDS reads: 8 distinct broadcast addresses/wave,
// conflict-free. Distance numerics bit-frozen (absmax 0.0 R1/R2/R4/R6/R8).
// ---------------------------------------------------------------------------
__global__ __launch_bounds__(256, 2) void vq_main(
    const float* __restrict__ feats, const float* __restrict__ emb,
    const float4* __restrict__ gSel, const u32* __restrict__ gOrd,
    const u32* __restrict__ gCnt, float* __restrict__ out_quant,
    float* __restrict__ out_idx, float* __restrict__ part)
{
    __shared__ float4 sSel[CAP];
    __shared__ u32    sOrd[CAP];
    __shared__ float  wsum[4];

    const int t = threadIdx.x, lane = t & 63, wave = t >> 6, csub = t & 7;

    const u32 cnt = gCnt[0];                              // wave-uniform
    const bool covered = (cnt > 0u) && (cnt <= (u32)CAP);
    const u32 padded = covered ? ((cnt + 7u) & ~7u) : 0u;

    for (u32 i = (u32)t; i < cnt && i < (u32)CAP; i += 256u) {
        sSel[i] = gSel[i]; sOrd[i] = gOrd[i];
    }
    if (covered && t < (int)(padded - cnt)) {             // pad with dup of entry 0
        sSel[cnt + t] = gSel[0]; sOrd[cnt + t] = gOrd[0];
    }
    __syncthreads();

    const int row = (blockIdx.x * 256 + t) >> 3;          // 32 rows/block
    const float x0 = feats[3*row+0], x1 = feats[3*row+1], x2 = feats[3*row+2];
    const float xx = __fadd_rn(__fadd_rn(__fmul_rn(x0,x0), __fmul_rn(x1,x1)),
                               __fmul_rn(x2,x2));         // frozen

    float BD = __int_as_float(0x7f800000);
    u32   BO = 0xffffffffu;

    for (u32 pos = (u32)csub; pos < padded; pos += 8u) {
        const float4 E = sSel[pos];
        const u32 orig = sOrd[pos];
        const float xe2 = __fmaf_rn(x2, E.z, __fmaf_rn(x1, E.y, __fmul_rn(x0, E.x)));
        const float d   = __fadd_rn(__fsub_rn(xx, xe2), E.w);       // frozen
        const bool bt = (d < BD) || (d == BD && orig < BO);         // exact lex
        if (bt) { BD = d; BO = orig; }
    }

    u64 k = ((u64)__float_as_uint(BD) << 32) | (u64)BO;
    { u64 o;
      o = __shfl_xor(k, 1, 64); if (o < k) k = o;
      o = __shfl_xor(k, 2, 64); if (o < k) k = o;
      o = __shfl_xor(k, 4, 64); if (o < k) k = o; }

    // prune check (margins validated R5/R6/R8): non-selected codes have ee<=THETA
    const float gb = __uint_as_float((u32)(k >> 32));
    const float sx = sqrtf(xx) - 1e-5f;
    const float T  = sx - (sqrtf(gb + 1e-4f) + 1e-5f);
    const float T2 = (T > 0.0f) ? (T*T - 1e-5f) : -1.0e30f;
    const bool fail = !covered || !(THETA < T2);

    if (__ballot(fail) != 0ull) {   // rare: exact wave-collective full scan
        for (int code = csub; code < VOCAB; code += 8) {
            const float e0 = emb[3*code+0], e1 = emb[3*code+1], e2 = emb[3*code+2];
            const float ee = __fadd_rn(__fadd_rn(__fmul_rn(e0,e0), __fmul_rn(e1,e1)),
                                       __fmul_rn(e2,e2));
            const float xe = __fmaf_rn(x2, e2, __fmaf_rn(x1, e1, __fmul_rn(x0, e0)));
            const float d  = __fadd_rn(__fsub_rn(xx, __fadd_rn(xe, xe)), ee);  // frozen
            const u32 orig = (u32)code;
            const bool bt = (d < BD) || (d == BD && orig < BO);
            if (bt) { BD = d; BO = orig; }
        }
        k = ((u64)__float_as_uint(BD) << 32) | (u64)BO;
        u64 o;
        o = __shfl_xor(k, 1, 64); if (o < k) k = o;
        o = __shfl_xor(k, 2, 64); if (o < k) k = o;
        o = __shfl_xor(k, 4, 64); if (o < k) k = o;
    }

    // epilogue: csub==0 lane emits its row; block loss partial
    float s = 0.0f;
    if (csub == 0) {
        const u32 idx = (u32)(k & 0xffffffffULL);
        const float e0 = emb[3*idx+0], e1 = emb[3*idx+1], e2 = emb[3*idx+2];
        out_quant[3*row+0] = __fadd_rn(x0, __fsub_rn(e0, x0));
        out_quant[3*row+1] = __fadd_rn(x1, __fsub_rn(e1, x1));
        out_quant[3*row+2] = __fadd_rn(x2, __fsub_rn(e2, x2));
        out_idx[row] = (float)idx;
        const float d0 = e0 - x0, d1 = e1 - x1, d2 = e2 - x2;
        s = d0*d0 + d1*d1 + d2*d2;
    }
    #pragma unroll
    for (int o = 1; o < 64; o <<= 1) s += __shfl_xor(s, o, 64);
    if (lane == 0) wsum[wave] = s;
    __syncthreads();
    if (t == 0) part[blockIdx.x] = (wsum[0] + wsum[1]) + (wsum[2] + wsum[3]);
}

// ---------------------------------------------------------------------------
__global__ __launch_bounds__(MGRID) void vq_loss(
    const float* __restrict__ part, float* __restrict__ out_loss)
{
    __shared__ float ws[MGRID / 64];
    const int t = threadIdx.x, lane = t & 63, wave = t >> 6;
    float s = part[t];
    #pragma unroll
    for (int o = 1; o < 64; o <<= 1) s += __shfl_xor(s, o, 64);
    if (lane == 0) ws[wave] = s;
    __syncthreads();
    if (t == 0) {
        float S = 0.0f;
        #pragma unroll
        for (int i = 0; i < MGRID / 64; ++i) S += ws[i];
        const float m = S / (float)(N_ROWS * 3);
        out_loss[0] = __fadd_rn(m, __fmul_rn(0.25f, m));
    }
}

extern "C" void kernel_launch(void* const* d_in, const int* in_sizes, int n_in,
                              void* d_out, int out_size, void* d_ws, size_t ws_size,
                              hipStream_t stream)
{
    const float* feats = (const float*)d_in[0];   // [4,4096,3] f32
    const float* emb   = (const float*)d_in[1];   // [8192,3]   f32
    float* out = (float*)d_out;

    char* ws = (char*)d_ws;
    float4* gSel = (float4*)(ws);
    u32*    gOrd = (u32*)(ws + 32768);
    u32*    gCnt = (u32*)(ws + 40960);
    float*  part = (float*)(ws + 41216);

    hipMemsetAsync(gCnt, 0, 4, stream);
    vq_prep<<<VOCAB / 256, 256, 0, stream>>>(emb, gSel, gOrd, gCnt);
    vq_main<<<MGRID, 256, 0, stream>>>(feats, emb, gSel, gOrd, gCnt,
                                       out, out + (size_t)N_ROWS * 3, part);
    vq_loss<<<1, MGRID, 0, stream>>>(part, out + (size_t)N_ROWS * 4);
}